// Round 1
// baseline (287.683 us; speedup 1.0000x reference)
//
#include <hip/hip_runtime.h>

// LongformerAttention on MI355X (gfx950), fp16 MFMA pipeline.
// Shapes: B=2 S=4096 E=1024 H=16 D=64 WIN=256. All GEMMs NT (both operands
// K-contiguous), 16x16x32 f16 MFMA, fp32 accum. Attention = flash-style with
// exp2-domain online softmax (log2e/8 folded into q scale at RoPE time).

typedef _Float16 half8 __attribute__((ext_vector_type(8)));
typedef _Float16 half4v __attribute__((ext_vector_type(4)));
typedef float floatx4 __attribute__((ext_vector_type(4)));

typedef __attribute__((address_space(3))) unsigned int lds_u32;
typedef const __attribute__((address_space(1))) unsigned int glb_u32;

__device__ __forceinline__ void async_copy16(const void* g, void* l) {
  // global -> LDS direct, 16 B/lane. LDS dest = wave-uniform base + lane*16.
  __builtin_amdgcn_global_load_lds((glb_u32*)g, (lds_u32*)l, 16, 0, 0);
}

// ---------------------------------------------------------------- convert
// x (8.4M f32) + Wq/Wk/Wv/Wo (1M f32 each) -> contiguous fp16 region at ws[0].
__global__ __launch_bounds__(256) void convert_kernel(
    const float* __restrict__ x, const float* __restrict__ wq,
    const float* __restrict__ wk, const float* __restrict__ wv,
    const float* __restrict__ wo, _Float16* __restrict__ dst) {
  const int e0 = (blockIdx.x * 256 + threadIdx.x) * 4;
  const float* src; int off;
  if      (e0 <  8388608) { src = x;  off = e0; }
  else if (e0 <  9437184) { src = wq; off = e0 -  8388608; }
  else if (e0 < 10485760) { src = wk; off = e0 -  9437184; }
  else if (e0 < 11534336) { src = wv; off = e0 - 10485760; }
  else                    { src = wo; off = e0 - 11534336; }
  const float4 f = *(const float4*)(src + off);
  half4v h;
  h[0] = (_Float16)f.x; h[1] = (_Float16)f.y;
  h[2] = (_Float16)f.z; h[3] = (_Float16)f.w;
  *(half4v*)(dst + e0) = h;
}

// ---------------------------------------------------------------- QKV GEMM
// out[m,n] = sum_k A[m,k]*W[n,k] + bias[n], written fp16 to [b,h,s,d].
// 128x128 tile, BK=32, 4 waves in 2x2 (64x64 each), global_load_lds staging
// with 2-bit XOR colblock swizzle (frag ds_read_b128 -> 2-way conflicts max).
__global__ __launch_bounds__(256, 2) void gemm_qkv_kernel(
    const _Float16* __restrict__ A, const _Float16* __restrict__ w0,
    const _Float16* __restrict__ w1, const _Float16* __restrict__ w2,
    const float* __restrict__ b0, const float* __restrict__ b1,
    const float* __restrict__ b2, _Float16* __restrict__ o0,
    _Float16* __restrict__ o1, _Float16* __restrict__ o2) {
  __shared__ _Float16 As[128 * 32];
  __shared__ _Float16 Bs[128 * 32];
  const int tid = threadIdx.x;
  const int w = tid >> 6, lane = tid & 63;
  const int l4 = lane & 15, quad = lane >> 4;
  const int wm = w & 1, wn = w >> 1;
  const int m0 = blockIdx.x * 128, n0 = blockIdx.y * 128;

  const _Float16* B; const float* bias; _Float16* out;
  if (blockIdx.z == 0)      { B = w0; bias = b0; out = o0; }
  else if (blockIdx.z == 1) { B = w1; bias = b1; out = o1; }
  else                      { B = w2; bias = b2; out = o2; }

  const floatx4 zero = {0.f, 0.f, 0.f, 0.f};
  floatx4 acc[4][4];
#pragma unroll
  for (int i = 0; i < 4; ++i)
#pragma unroll
    for (int j = 0; j < 4; ++j) acc[i][j] = zero;

  const int fcb = (quad ^ ((l4 >> 2) & 3)) * 8;  // swizzled frag colblock

  for (int kt = 0; kt < 32; ++kt) {
    const int k0 = kt * 32;
#pragma unroll
    for (int i = 0; i < 2; ++i) {
      const int p = i * 256 + tid;
      const int r = p >> 2;
      const int cb = (p & 3) ^ ((r >> 2) & 3);
      async_copy16(A + (m0 + r) * 1024 + k0 + cb * 8, As + (i * 256 + w * 64) * 8);
      async_copy16(B + (n0 + r) * 1024 + k0 + cb * 8, Bs + (i * 256 + w * 64) * 8);
    }
    __syncthreads();
    half8 af[4], bf[4];
#pragma unroll
    for (int mt = 0; mt < 4; ++mt)
      af[mt] = *(const half8*)(As + (wm * 64 + mt * 16 + l4) * 32 + fcb);
#pragma unroll
    for (int nt = 0; nt < 4; ++nt)
      bf[nt] = *(const half8*)(Bs + (wn * 64 + nt * 16 + l4) * 32 + fcb);
#pragma unroll
    for (int mt = 0; mt < 4; ++mt)
#pragma unroll
      for (int nt = 0; nt < 4; ++nt)
        acc[mt][nt] = __builtin_amdgcn_mfma_f32_16x16x32_f16(af[mt], bf[nt], acc[mt][nt], 0, 0, 0);
    __syncthreads();
  }

#pragma unroll
  for (int nt = 0; nt < 4; ++nt) {
    const int n = n0 + wn * 64 + nt * 16 + l4;
    const float bval = bias[n];
    const int hh = n >> 6, dd = n & 63;
#pragma unroll
    for (int mt = 0; mt < 4; ++mt)
#pragma unroll
      for (int r = 0; r < 4; ++r) {
        const int m = m0 + wm * 64 + mt * 16 + quad * 4 + r;  // C row = quad*4+reg
        const int bb = m >> 12, s = m & 4095;
        out[((bb * 16 + hh) * 4096 + s) * 64 + dd] = (_Float16)(acc[mt][nt][r] + bval);
      }
  }
}

// ---------------------------------------------------------------- out GEMM
__global__ __launch_bounds__(256, 2) void gemm_out_kernel(
    const _Float16* __restrict__ A, const _Float16* __restrict__ B,
    const float* __restrict__ bias, float* __restrict__ out) {
  __shared__ _Float16 As[128 * 32];
  __shared__ _Float16 Bs[128 * 32];
  const int tid = threadIdx.x;
  const int w = tid >> 6, lane = tid & 63;
  const int l4 = lane & 15, quad = lane >> 4;
  const int wm = w & 1, wn = w >> 1;
  const int m0 = blockIdx.x * 128, n0 = blockIdx.y * 128;

  const floatx4 zero = {0.f, 0.f, 0.f, 0.f};
  floatx4 acc[4][4];
#pragma unroll
  for (int i = 0; i < 4; ++i)
#pragma unroll
    for (int j = 0; j < 4; ++j) acc[i][j] = zero;

  const int fcb = (quad ^ ((l4 >> 2) & 3)) * 8;

  for (int kt = 0; kt < 32; ++kt) {
    const int k0 = kt * 32;
#pragma unroll
    for (int i = 0; i < 2; ++i) {
      const int p = i * 256 + tid;
      const int r = p >> 2;
      const int cb = (p & 3) ^ ((r >> 2) & 3);
      async_copy16(A + (m0 + r) * 1024 + k0 + cb * 8, As + (i * 256 + w * 64) * 8);
      async_copy16(B + (n0 + r) * 1024 + k0 + cb * 8, Bs + (i * 256 + w * 64) * 8);
    }
    __syncthreads();
    half8 af[4], bf[4];
#pragma unroll
    for (int mt = 0; mt < 4; ++mt)
      af[mt] = *(const half8*)(As + (wm * 64 + mt * 16 + l4) * 32 + fcb);
#pragma unroll
    for (int nt = 0; nt < 4; ++nt)
      bf[nt] = *(const half8*)(Bs + (wn * 64 + nt * 16 + l4) * 32 + fcb);
#pragma unroll
    for (int mt = 0; mt < 4; ++mt)
#pragma unroll
      for (int nt = 0; nt < 4; ++nt)
        acc[mt][nt] = __builtin_amdgcn_mfma_f32_16x16x32_f16(af[mt], bf[nt], acc[mt][nt], 0, 0, 0);
    __syncthreads();
  }

#pragma unroll
  for (int nt = 0; nt < 4; ++nt) {
    const int n = n0 + wn * 64 + nt * 16 + l4;
    const float bval = bias[n];
#pragma unroll
    for (int mt = 0; mt < 4; ++mt)
#pragma unroll
      for (int r = 0; r < 4; ++r) {
        const int m = m0 + wm * 64 + mt * 16 + quad * 4 + r;
        out[m * 1024 + n] = acc[mt][nt][r] + bval;
      }
  }
}

// ---------------------------------------------------------------- RoPE
// Reference quirk: rotation angle depends on HEAD index, not seq position:
// angle(h,j) = h * 10000^(-(j mod 32)/32); interleaved pair rotation.
// q additionally scaled by log2(e)/8 (softmax in exp2 domain, /sqrt(64)).
__global__ __launch_bounds__(256) void rope_kernel(_Float16* __restrict__ q,
                                                   _Float16* __restrict__ k) {
  const int gid = blockIdx.x * 256 + threadIdx.x;
  _Float16* p; float scl; int id;
  if (gid < 4194304) { p = q; scl = 0.18033688f; id = gid; }
  else               { p = k; scl = 1.0f;        id = gid - 4194304; }
  const int dp = id & 31;
  const int rest = id >> 5;            // (b*16+h)*4096 + s
  const int h = (rest >> 12) & 15;
  const int j0 = dp * 2;
  const float f0 = __expf((float)(j0 & 31) * -0.28782314f);        // ln(1e4)/32
  const float f1 = __expf((float)((j0 + 1) & 31) * -0.28782314f);
  float s0, c0, s1, c1;
  __sincosf((float)h * f0, &s0, &c0);
  __sincosf((float)h * f1, &s1, &c1);
  _Float16* ptr = p + rest * 64 + j0;
  const float x0 = (float)ptr[0], x1 = (float)ptr[1];
  ptr[0] = (_Float16)((x0 * c0 - x1 * s0) * scl);
  ptr[1] = (_Float16)((x1 * c1 + x0 * s1) * scl);
}

// ---------------------------------------------------------------- V transpose
// [bh][s][64] -> [bh][64][s] so PV's B-operand frags are key-contiguous.
__global__ __launch_bounds__(256) void transpose_v(const _Float16* __restrict__ v,
                                                   _Float16* __restrict__ vt) {
  __shared__ _Float16 tile[64 * 70];  // stride 70 halfs = 35 words (odd) vs banks
  const int t = threadIdx.x;
  const int bh = blockIdx.y, s0 = blockIdx.x * 64;
  const _Float16* src = v + (bh * 4096 + s0) * 64;
#pragma unroll
  for (int i = 0; i < 2; ++i) {
    const int c = i * 256 + t;
    const int row = c >> 3, cb = c & 7;
    const half8 d = *(const half8*)(src + row * 64 + cb * 8);
#pragma unroll
    for (int u = 0; u < 8; ++u) tile[(cb * 8 + u) * 70 + row] = d[u];
  }
  __syncthreads();
  _Float16* dst = vt + bh * 262144 + s0;
#pragma unroll
  for (int i = 0; i < 2; ++i) {
    const int c = i * 256 + t;
    const int dd = c >> 3, scb = c & 7;
    half8 d;
#pragma unroll
    for (int u = 0; u < 8; ++u) d[u] = tile[dd * 70 + scb * 8 + u];
    *(half8*)(dst + dd * 4096 + scb * 8) = d;
  }
}

// ---------------------------------------------------------------- attention
// One block per (128 q-rows, b*h). 4 waves, each owns 32 q-rows. 5 kv-tiles of
// 128 keys covering [q0-256, q0+384). Band mask |kpos-qpos|<=256 only on
// tiles 0/4. P goes C-layout -> LDS -> A-layout (m120-verified transform).
__global__ __launch_bounds__(256, 2) void attn_kernel(
    const _Float16* __restrict__ qg, const _Float16* __restrict__ kg,
    const _Float16* __restrict__ vtg, _Float16* __restrict__ ctx) {
  __shared__ _Float16 Ks[128 * 64];
  __shared__ _Float16 Vs[64 * 128];
  __shared__ _Float16 Ps[4 * 32 * 136];  // stride 136 halfs: 16B-aligned rows, 2-way max

  const int tid = threadIdx.x;
  const int w = tid >> 6, lane = tid & 63;
  const int l4 = lane & 15, quad = lane >> 4;
  const int q0 = blockIdx.x * 128;
  const int bh = blockIdx.y;
  const _Float16* qbh = qg + bh * 262144;
  const _Float16* kbh = kg + bh * 262144;
  const _Float16* vbh = vtg + bh * 262144;
  _Float16* Pw = Ps + w * (32 * 136);

  half8 qf[2][2];  // Q frags stay in registers (read once per block)
#pragma unroll
  for (int mt = 0; mt < 2; ++mt)
#pragma unroll
    for (int ks = 0; ks < 2; ++ks)
      qf[mt][ks] = *(const half8*)(qbh + (q0 + w * 32 + mt * 16 + l4) * 64 + ks * 32 + quad * 8);

  const floatx4 zero = {0.f, 0.f, 0.f, 0.f};
  floatx4 O[2][4];
  float m_st[2][4], l_st[2][4], alpha[2][4];
#pragma unroll
  for (int mt = 0; mt < 2; ++mt) {
#pragma unroll
    for (int nd = 0; nd < 4; ++nd) O[mt][nd] = zero;
#pragma unroll
    for (int r = 0; r < 4; ++r) { m_st[mt][r] = -1e30f; l_st[mt][r] = 0.f; }
  }

  for (int t = 0; t < 5; ++t) {
    const int kv0 = q0 + (t - 2) * 128;
    if (kv0 < 0 || kv0 >= 4096) continue;  // block-uniform

    // stage K [128 keys][64 d] and Vt [64 d][128 keys], 3-bit XOR swizzle
#pragma unroll
    for (int i = 0; i < 4; ++i) {
      const int p = i * 256 + tid;
      const int rk = p >> 3, ck = (p & 7) ^ (rk & 7);
      async_copy16(kbh + (kv0 + rk) * 64 + ck * 8, Ks + (i * 256 + w * 64) * 8);
      const int rv = p >> 4, cv = (p & 15) ^ (rv & 7);
      async_copy16(vbh + rv * 4096 + kv0 + cv * 8, Vs + (i * 256 + w * 64) * 8);
    }
    __syncthreads();

    // S = Q K^T  (wave: 32 q-rows x 128 keys)
    floatx4 S[2][8];
#pragma unroll
    for (int mt = 0; mt < 2; ++mt)
#pragma unroll
      for (int nt = 0; nt < 8; ++nt) S[mt][nt] = zero;
#pragma unroll
    for (int ks = 0; ks < 2; ++ks)
#pragma unroll
      for (int nt = 0; nt < 8; ++nt) {
        const int key = nt * 16 + l4;
        const half8 bf = *(const half8*)(Ks + key * 64 + ((ks * 4 + quad) ^ (l4 & 7)) * 8);
#pragma unroll
        for (int mt = 0; mt < 2; ++mt)
          S[mt][nt] = __builtin_amdgcn_mfma_f32_16x16x32_f16(qf[mt][ks], bf, S[mt][nt], 0, 0, 0);
      }

    if (t == 0 || t == 4) {  // only edge tiles are banded
#pragma unroll
      for (int mt = 0; mt < 2; ++mt)
#pragma unroll
        for (int r = 0; r < 4; ++r) {
          const int qpos = q0 + w * 32 + mt * 16 + quad * 4 + r;
#pragma unroll
          for (int nt = 0; nt < 8; ++nt) {
            const int d = (kv0 + nt * 16 + l4) - qpos;
            if (d < -256 || d > 256) S[mt][nt][r] = -1e30f;
          }
        }
    }

    // online softmax (exp2 domain; scores pre-scaled by log2e/8)
#pragma unroll
    for (int mt = 0; mt < 2; ++mt)
#pragma unroll
      for (int r = 0; r < 4; ++r) {
        float mx = S[mt][0][r];
#pragma unroll
        for (int nt = 1; nt < 8; ++nt) mx = fmaxf(mx, S[mt][nt][r]);
#pragma unroll
        for (int off = 1; off < 16; off <<= 1) mx = fmaxf(mx, __shfl_xor(mx, off, 16));
        const float mnew = fmaxf(m_st[mt][r], mx);
        alpha[mt][r] = exp2f(m_st[mt][r] - mnew);
        m_st[mt][r] = mnew;
        float rs = 0.f;
#pragma unroll
        for (int nt = 0; nt < 8; ++nt) {
          const float pv = exp2f(S[mt][nt][r] - mnew);
          S[mt][nt][r] = pv;
          rs += pv;
        }
#pragma unroll
        for (int off = 1; off < 16; off <<= 1) rs += __shfl_xor(rs, off, 16);
        l_st[mt][r] = l_st[mt][r] * alpha[mt][r] + rs;
      }

#pragma unroll
    for (int mt = 0; mt < 2; ++mt)
#pragma unroll
      for (int nd = 0; nd < 4; ++nd)
#pragma unroll
        for (int r = 0; r < 4; ++r) O[mt][nd][r] *= alpha[mt][r];

    // P: C-layout -> LDS (wave-private region; no block barrier needed)
#pragma unroll
    for (int mt = 0; mt < 2; ++mt)
#pragma unroll
      for (int nt = 0; nt < 8; ++nt)
#pragma unroll
        for (int r = 0; r < 4; ++r)
          Pw[(mt * 16 + quad * 4 + r) * 136 + nt * 16 + l4] = (_Float16)S[mt][nt][r];

    // O += P V
#pragma unroll
    for (int ks = 0; ks < 4; ++ks) {
      half8 pa[2];
#pragma unroll
      for (int mt = 0; mt < 2; ++mt)
        pa[mt] = *(const half8*)(Pw + (mt * 16 + l4) * 136 + ks * 32 + quad * 8);
#pragma unroll
      for (int nd = 0; nd < 4; ++nd) {
        const int dd = nd * 16 + l4;
        const half8 vf = *(const half8*)(Vs + dd * 128 + ((ks * 4 + quad) ^ (l4 & 7)) * 8);
#pragma unroll
        for (int mt = 0; mt < 2; ++mt)
          O[mt][nd] = __builtin_amdgcn_mfma_f32_16x16x32_f16(pa[mt], vf, O[mt][nd], 0, 0, 0);
      }
    }
    __syncthreads();  // protect Ks/Vs before next tile's staging
  }

  const int b = bh >> 4, hh = bh & 15;
#pragma unroll
  for (int mt = 0; mt < 2; ++mt)
#pragma unroll
    for (int r = 0; r < 4; ++r) {
      const int s = q0 + w * 32 + mt * 16 + quad * 4 + r;
      const float inv_l = 1.f / l_st[mt][r];
#pragma unroll
      for (int nd = 0; nd < 4; ++nd) {
        const int dd = nd * 16 + l4;
        ctx[(b * 4096 + s) * 1024 + hh * 64 + dd] = (_Float16)(O[mt][nd][r] * inv_l);
      }
    }
}

// ---------------------------------------------------------------- launch
extern "C" void kernel_launch(void* const* d_in, const int* in_sizes, int n_in,
                              void* d_out, int out_size, void* d_ws, size_t ws_size,
                              hipStream_t stream) {
  const float* x  = (const float*)d_in[0];
  const float* Wq = (const float*)d_in[1];
  const float* bq = (const float*)d_in[2];
  const float* Wk = (const float*)d_in[3];
  const float* bk = (const float*)d_in[4];
  const float* Wv = (const float*)d_in[5];
  const float* bv = (const float*)d_in[6];
  const float* Wo = (const float*)d_in[7];
  const float* bo = (const float*)d_in[8];

  _Float16* ws   = (_Float16*)d_ws;       // all offsets in halfs
  _Float16* xh   = ws;                    // 8388608
  _Float16* wqh  = ws + 8388608;          // 1048576 each
  _Float16* wkh  = ws + 9437184;
  _Float16* wvh  = ws + 10485760;
  _Float16* woh  = ws + 11534336;
  _Float16* qh   = ws + 12582912;         // [b,h,s,d] fp16
  _Float16* kh   = ws + 20971520;
  _Float16* vh   = ws + 29360128;
  _Float16* vth  = ws + 37748736;         // [b,h,d,s]
  _Float16* ctxh = xh;                    // reuse: x dead after QKV GEMM
  // total ws use: 46137344 halfs = 92.3 MB

  convert_kernel<<<12288, 256, 0, stream>>>(x, Wq, Wk, Wv, Wo, ws);
  gemm_qkv_kernel<<<dim3(64, 8, 3), 256, 0, stream>>>(xh, wqh, wkh, wvh,
                                                      bq, bk, bv, qh, kh, vh);
  rope_kernel<<<32768, 256, 0, stream>>>(qh, kh);
  transpose_v<<<dim3(64, 32), 256, 0, stream>>>(vh, vth);
  attn_kernel<<<dim3(32, 32), 256, 0, stream>>>(qh, kh, vth, ctxh);
  gemm_out_kernel<<<dim3(64, 8), 256, 0, stream>>>(ctxh, woh, bo, (float*)d_out);
}